// Round 5
// baseline (498.579 us; speedup 1.0000x reference)
//
#include <hip/hip_runtime.h>
#include <hip/hip_bf16.h>

typedef __hip_bfloat16 bf16;
typedef __bf16 bf16x8 __attribute__((ext_vector_type(8)));
typedef __bf16 bf16x4 __attribute__((ext_vector_type(4)));
typedef __bf16 bf16x2 __attribute__((ext_vector_type(2)));
typedef float f32x4 __attribute__((ext_vector_type(4)));

static constexpr int Bq = 4, Tq = 2048, Dq = 1024;

__device__ inline float b2f(bf16 h) { return __bfloat162float(h); }
__device__ inline bf16 f2b(float f) { return __float2bfloat16(f); }

// async global->LDS, 16 B per lane. LDS dst = wave-uniform base + lane*16.
__device__ __forceinline__ void gload_lds16(const bf16* g, bf16* lds_wave_base) {
    __builtin_amdgcn_global_load_lds((const __attribute__((address_space(1))) void*)g,
                                     (__attribute__((address_space(3))) void*)lds_wave_base,
                                     16, 0, 0);
}

// fast tanh-approx GELU: x * sigmoid(1.5957691x + 0.0713548x^3), via exp2+rcp
__device__ __forceinline__ float fast_gelu(float x) {
    float u = x * (0.7978845608028654f + 0.03567740814183427f * x * x);
    float e = __builtin_amdgcn_exp2f(-2.885390081777927f * u);
    return x * __builtin_amdgcn_rcpf(1.f + e);
}

__device__ inline void ld4f(const float* p, float* v) {
    float4 t = *reinterpret_cast<const float4*>(p);
    v[0] = t.x; v[1] = t.y; v[2] = t.z; v[3] = t.w;
}
__device__ inline void ld4f(const bf16* p, float* v) {
    bf16x4 t = *reinterpret_cast<const bf16x4*>(p);
    v[0] = (float)t[0]; v[1] = (float)t[1]; v[2] = (float)t[2]; v[3] = (float)t[3];
}

// ---------------- LayerNorm body (one block per row, D=1024), fp32 gamma/beta ----------------
template <typename Tin>
__device__ __forceinline__ void ln_body(const Tin* __restrict__ x, const float* __restrict__ g,
                                        const float* __restrict__ b, bf16* __restrict__ out,
                                        int row, float* sred)
{
    const int tid = threadIdx.x;
    const int s0 = tid * 4;
    const Tin* xr = x + (size_t)row * Dq;
    bf16* orow = out + (size_t)row * Dq;
    float v[4], gv[4], bv[4];
    ld4f(xr + s0, v);
    ld4f(g + s0, gv);
    ld4f(b + s0, bv);
    float sum = v[0] + v[1] + v[2] + v[3];
    float sq = v[0]*v[0] + v[1]*v[1] + v[2]*v[2] + v[3]*v[3];
    for (int o = 32; o > 0; o >>= 1) { sum += __shfl_xor(sum, o); sq += __shfl_xor(sq, o); }
    const int w = tid >> 6;
    if ((tid & 63) == 0) { sred[w] = sum; sred[4 + w] = sq; }
    __syncthreads();
    const float ts = sred[0] + sred[1] + sred[2] + sred[3];
    const float tq = sred[4] + sred[5] + sred[6] + sred[7];
    const float mean = ts / Dq;
    const float rs = rsqrtf(tq / Dq - mean * mean + 1e-5f);
    bf16x4 o4;
    #pragma unroll
    for (int i = 0; i < 4; ++i) o4[i] = (__bf16)((v[i] - mean) * rs * gv[i] + bv[i]);
    *reinterpret_cast<bf16x4*>(orow + s0) = o4;
}

__global__ void ln_kernel(const bf16* __restrict__ x, const float* __restrict__ g,
                          const float* __restrict__ b, bf16* __restrict__ out)
{
    __shared__ float sred[8];
    ln_body(x, g, b, out, blockIdx.x, sred);
}

// ---------------- prep: LN1 (8192 blocks) + 4 weight transposes (3072 tile-blocks) ----------------
__global__ void prep_kernel(const float* __restrict__ x, const float* __restrict__ g,
                            const float* __restrict__ b, bf16* __restrict__ h,
                            const float* __restrict__ Wqkv, bf16* __restrict__ WqkvT,
                            const float* __restrict__ Wproj, bf16* __restrict__ WprojT,
                            const float* __restrict__ W1, bf16* __restrict__ W1T,
                            const float* __restrict__ W2, bf16* __restrict__ W2T)
{
    __shared__ float smem[64 * 65];
    int id = blockIdx.x;
    if (id < 8192) { ln_body(x, g, b, h, id, smem); return; }
    id -= 8192;
    const float* src; bf16* dst; long ldin, ldout; int gx;
    if (id < 768)       { src = Wqkv;  dst = WqkvT;  ldin = 3072; ldout = 1024; gx = 48; }
    else if (id < 1024) { id -= 768;  src = Wproj; dst = WprojT; ldin = 1024; ldout = 1024; gx = 16; }
    else if (id < 2048) { id -= 1024; src = W1;    dst = W1T;    ldin = 4096; ldout = 1024; gx = 64; }
    else                { id -= 2048; src = W2;    dst = W2T;    ldin = 1024; ldout = 4096; gx = 16; }
    const int c0 = (id % gx) * 64, r0 = (id / gx) * 64;
    const int tid = threadIdx.x;
    const int tx = tid & 63, ty = tid >> 6;
    float (*tile)[65] = reinterpret_cast<float(*)[65]>(smem);
    #pragma unroll
    for (int i = 0; i < 16; ++i) {
        int r = ty + i * 4;
        tile[r][tx] = src[(size_t)(r0 + r) * ldin + c0 + tx];
    }
    __syncthreads();
    const int px = tid & 31, cy = tid >> 5;
    #pragma unroll
    for (int i = 0; i < 8; ++i) {
        int cc = cy + i * 8;
        bf16x2 p;
        p[0] = (__bf16)tile[px * 2][cc];
        p[1] = (__bf16)tile[px * 2 + 1][cc];
        *reinterpret_cast<bf16x2*>(&dst[(size_t)(c0 + cc) * ldout + r0 + px * 2]) = p;
    }
}

// ---------------- 128x128 LDS-staged MFMA GEMM, BK=64 (R8 inner loop) ----------------
// C = act(scale * A @ Bt^T + bias). A:[M,K] (lda), Bt:[N,K] (ldb), bf16.
// ACT: 0 none, 1 gelu, 2 exp2 w/ causal mask. TRI: lower-triangle grid decode;
//      blocks 136..647 of a TRI dispatch do the V->V^T transpose instead.
// CK: truncate K at m0+128 (attn@V). FR: fused row-sum via all-ones-B MFMA.
template <int ACT, int TRI, int CK, int FR>
__global__ void gemm128(const bf16* __restrict__ A, const bf16* __restrict__ Bt,
                        const float* __restrict__ bias,
                        bf16* __restrict__ Cb, float* __restrict__ Cf,
                        int K, long lda, long ldb, long ldc,
                        long sA, long sB, long sC, float scale,
                        const bf16* __restrict__ vsrc, bf16* __restrict__ vdst)
{
    __shared__ bf16 As[128 * 64];
    __shared__ bf16 Bs[128 * 64];

    int bx, by;
    if (TRI) {
        const int lin = blockIdx.x;
        if (lin >= 136) {
            // ---- fused V -> V^T 64x64 tile transpose (V cols of kqv); 512 tiles/batch ----
            const int idx = lin - 136;
            const int c0 = (idx & 15) * 64, r0 = (idx >> 4) * 64;
            const bf16* ip = vsrc + (size_t)blockIdx.z * ((size_t)Tq * 3072);
            bf16* op = vdst + (size_t)blockIdx.z * ((size_t)Dq * Tq);
            bf16 (*tile)[66] = reinterpret_cast<bf16(*)[66]>(As);
            const int tid = threadIdx.x;
            const int tx = tid & 31, ty = tid >> 5;
            #pragma unroll
            for (int i = 0; i < 8; ++i) {
                int r = ty + i * 8;
                *reinterpret_cast<bf16x2*>(&tile[r][tx * 2]) =
                    *reinterpret_cast<const bf16x2*>(&ip[(size_t)(r0 + r) * 3072 + c0 + tx * 2]);
            }
            __syncthreads();
            #pragma unroll
            for (int i = 0; i < 8; ++i) {
                int cc = ty + i * 8;
                bf16x2 p;
                p[0] = tile[tx * 2][cc];
                p[1] = tile[tx * 2 + 1][cc];
                *reinterpret_cast<bf16x2*>(&op[(size_t)(c0 + cc) * 2048 + r0 + tx * 2]) = p;
            }
            return;
        }
        int t = (int)((sqrtf(8.f * lin + 1.f) - 1.f) * 0.5f);
        while ((t + 1) * (t + 2) / 2 <= lin) ++t;
        while (t * (t + 1) / 2 > lin) --t;
        by = t; bx = lin - t * (t + 1) / 2;
    } else {
        // XCD-banded remap (bijective; gy % 8 == 0 for all our grids)
        const int gx = gridDim.x, gy = gridDim.y;
        const int lin = blockIdx.x + gx * blockIdx.y;
        const int band = lin & 7;
        const int idx = lin >> 3;
        bx = idx % gx;
        by = band * (gy >> 3) + idx / gx;
    }

    const int m0 = by * 128, n0 = bx * 128;
    const int Kend = CK ? min(K, m0 + 128) : K;

    const bf16* Ab = A + (size_t)blockIdx.z * sA;
    const bf16* Bb = Bt + (size_t)blockIdx.z * sB;
    const int tid = threadIdx.x;
    const int wid = tid >> 6, lane = tid & 63;
    const int wr = wid >> 1, wc = wid & 1;
    const int l15 = lane & 15, quad = lane >> 4;

    const int rloc = lane >> 3, slot = lane & 7;
    const bf16* agp = Ab + (size_t)(m0 + wid * 32 + rloc) * lda + (slot ^ rloc) * 8;
    const bf16* bgp = Bb + (size_t)(n0 + wid * 32 + rloc) * ldb + (slot ^ rloc) * 8;
    bf16* awb = As + wid * 32 * 64;
    bf16* bwb = Bs + wid * 32 * 64;

    const int afo = (wr * 64 + l15) * 64 + ((quad ^ (l15 & 7)) * 8);
    const int bfo = (wc * 64 + l15) * 64 + ((quad ^ (l15 & 7)) * 8);

    f32x4 acc[4][4];
    #pragma unroll
    for (int i = 0; i < 4; ++i)
        #pragma unroll
        for (int j = 0; j < 4; ++j) acc[i][j] = (f32x4){0.f, 0.f, 0.f, 0.f};

    f32x4 acc_l[4];
    bf16x8 ones;
    if (FR) {
        #pragma unroll
        for (int i = 0; i < 4; ++i) acc_l[i] = (f32x4){0.f, 0.f, 0.f, 0.f};
        #pragma unroll
        for (int i = 0; i < 8; ++i) ones[i] = (__bf16)1.0f;
    }

    for (int k0 = 0; k0 < Kend; k0 += 64) {
        #pragma unroll
        for (int i = 0; i < 4; ++i) {
            gload_lds16(agp + k0 + (size_t)(i * 8) * lda, awb + i * 8 * 64);
            gload_lds16(bgp + k0 + (size_t)(i * 8) * ldb, bwb + i * 8 * 64);
        }
        __syncthreads();

        bf16x8 af0[4], bf0[4], af1[4], bf1[4];
        #pragma unroll
        for (int i = 0; i < 4; ++i) {
            af0[i] = *reinterpret_cast<const bf16x8*>(As + (afo ^ 0)  + i * 1024);
            af1[i] = *reinterpret_cast<const bf16x8*>(As + (afo ^ 32) + i * 1024);
        }
        #pragma unroll
        for (int j = 0; j < 4; ++j) {
            bf0[j] = *reinterpret_cast<const bf16x8*>(Bs + (bfo ^ 0)  + j * 1024);
            bf1[j] = *reinterpret_cast<const bf16x8*>(Bs + (bfo ^ 32) + j * 1024);
        }
        #pragma unroll
        for (int i = 0; i < 4; ++i)
            #pragma unroll
            for (int j = 0; j < 4; ++j)
                acc[i][j] = __builtin_amdgcn_mfma_f32_16x16x32_bf16(af0[i], bf0[j], acc[i][j], 0, 0, 0);
        if (FR) {
            #pragma unroll
            for (int i = 0; i < 4; ++i)
                acc_l[i] = __builtin_amdgcn_mfma_f32_16x16x32_bf16(af0[i], ones, acc_l[i], 0, 0, 0);
        }
        #pragma unroll
        for (int i = 0; i < 4; ++i)
            #pragma unroll
            for (int j = 0; j < 4; ++j)
                acc[i][j] = __builtin_amdgcn_mfma_f32_16x16x32_bf16(af1[i], bf1[j], acc[i][j], 0, 0, 0);
        if (FR) {
            #pragma unroll
            for (int i = 0; i < 4; ++i)
                acc_l[i] = __builtin_amdgcn_mfma_f32_16x16x32_bf16(af1[i], ones, acc_l[i], 0, 0, 0);
        }

        __syncthreads();
    }

    #pragma unroll
    for (int i = 0; i < 4; ++i) {
        const int row = m0 + wr * 64 + i * 16 + quad * 4;
        #pragma unroll
        for (int j = 0; j < 4; ++j) {
            const int col = n0 + wc * 64 + j * 16 + l15;
            const float bv = bias ? bias[col] : 0.f;
            #pragma unroll
            for (int r = 0; r < 4; ++r) {
                float vv = scale * acc[i][j][r] + bv;
                if (ACT == 1) vv = fast_gelu(vv);
                else if (ACT == 2)
                    vv = (col <= row + r) ? __builtin_amdgcn_exp2f(1.4426950408889634f * vv) : 0.f;
                if (FR) vv *= __builtin_amdgcn_rcpf(acc_l[i][r]);
                const size_t idx2 = (size_t)(row + r) * ldc + col + (size_t)blockIdx.z * sC;
                if (Cf) Cf[idx2] = vv;
                else    Cb[idx2] = f2b(vv);
            }
        }
    }
}

// ---------------- 256x256 phase-rhythm MFMA GEMM, BK=64 (v5) ----------------
// 512 threads = 8 waves (2M x 4N), per-wave C = 128x64. Ring-2 LDS (128 KiB, 1 blk/CU).
// v5 combines the three independently-validated requirements:
//  (1) 24 ds_read_b128/wave/tile (B0 held P1->P3, B1 P2->P4): LDS pipe 2304 cyc
//      < MFMA 2480 cyc per tile per CU -> overlappable to MFMA-bound.
//  (2) m201 phase rhythm: 4 phases x {reads -> s_barrier -> lgkmcnt(0) ->
//      setprio(1) + 16 MFMA + setprio(0) -> s_barrier}. With 2 waves/SIMD the
//      partner wave's reads issue under this wave's MFMA cluster (anti-phasing;
//      setprio arbitration is what makes the split real, m218b).
//  (3) full-tile prefetch: all 8 stage loads for tile t+1 issued at t's P1 (bq
//      is fully free: its last reads were consumed before t-1's end barrier);
//      single vmcnt(0) at t's P4 = ~3.5 phases (~2000 cyc) cover > HBM 900.
// Cross-wave hazards all reduce to {consumed reads -> tile-end barrier -> write}
// or {vmcnt(0) -> tile-end barrier -> read}. VGPR est ~222 (<256 cap, no spill).
template <int ACT>
__global__ __launch_bounds__(512) void gemm256(
        const bf16* __restrict__ A, const bf16* __restrict__ Bt,
        const float* __restrict__ bias, bf16* __restrict__ C,
        int K, long lda, long ldb, long ldc)
{
    __shared__ bf16 As[2][256 * 64];
    __shared__ bf16 Bs[2][256 * 64];

    // XCD-banded remap (gy % 8 == 0 for all our grids)
    const int gx = gridDim.x, gy = gridDim.y;
    const int lin = blockIdx.x + gx * blockIdx.y;
    const int band = lin & 7;
    const int idx = lin >> 3;
    const int bx = idx % gx;
    const int by = band * (gy >> 3) + idx / gx;
    const int m0 = by * 256, n0 = bx * 256;

    const int tid = threadIdx.x;
    const int wid = tid >> 6, lane = tid & 63;
    const int wr = wid >> 2, wc = wid & 3;
    const int l15 = lane & 15, quad = lane >> 4;
    const int rloc = lane >> 3, slot = lane & 7;

    // staging: issue R covers tile rows [R, R+64); wave wid stages rows R+wid*8..+8
    const bf16* agp = A + (size_t)(m0 + wid * 8 + rloc) * lda + (slot ^ rloc) * 8;
    const bf16* bgp = Bt + (size_t)(n0 + wid * 8 + rloc) * ldb + (slot ^ rloc) * 8;

    auto issueA = [&](int buf, int t2, int R) {
        gload_lds16(agp + (size_t)R * lda + t2 * 64, &As[buf][(R + wid * 8) * 64]);
    };
    auto issueB = [&](int buf, int t2, int R) {
        gload_lds16(bgp + (size_t)R * ldb + t2 * 64, &Bs[buf][(R + wid * 8) * 64]);
    };

    // fragment offsets (elements): A row = wr*128 + rh*64 + i*16 + l15;
    // B row = wc*64 + j*16 + l15; k-slice selects granule via XOR 32.
    const int xg = (quad ^ (l15 & 7)) * 8;
    const int afo = (wr * 128 + l15) * 64 + xg;
    const int bfo = (wc * 64 + l15) * 64 + xg;

    f32x4 acc[8][4];
    #pragma unroll
    for (int i = 0; i < 8; ++i)
        #pragma unroll
        for (int j = 0; j < 4; ++j) acc[i][j] = (f32x4){0.f, 0.f, 0.f, 0.f};

    bf16x8 aA[4], aB[4], B0[4], B1[4];   // A per-phase; B0 live P1->P3, B1 P2->P4

    const int nt = K >> 6;   // even for all our shapes (K=1024)

#define RD_A(buf, rh, ks, dst)                                                            \
    { _Pragma("unroll")                                                                   \
      for (int i_ = 0; i_ < 4; ++i_)                                                      \
          dst[i_] = *reinterpret_cast<const bf16x8*>(                                     \
              &As[buf][(afo + (rh) * 4096 + i_ * 1024) ^ ((ks) * 32)]); }
#define RD_B(buf, ks, dst)                                                                \
    { _Pragma("unroll")                                                                   \
      for (int j_ = 0; j_ < 4; ++j_)                                                      \
          dst[j_] = *reinterpret_cast<const bf16x8*>(                                     \
              &Bs[buf][(bfo + j_ * 1024) ^ ((ks) * 32)]); }
#define MF16(rh, Aset, Bset)                                                              \
    { __builtin_amdgcn_s_setprio(1);                                                      \
      _Pragma("unroll")                                                                   \
      for (int i_ = 0; i_ < 4; ++i_)                                                      \
          _Pragma("unroll")                                                               \
          for (int j_ = 0; j_ < 4; ++j_)                                                  \
              acc[(rh) * 4 + i_][j_] = __builtin_amdgcn_mfma_f32_16x16x32_bf16(           \
                  Aset[i_], Bset[j_], acc[(rh) * 4 + i_][j_], 0, 0, 0);                   \
      __builtin_amdgcn_s_setprio(0); }
#define STAGE8(buf, t2)                                                                   \
    { issueA(buf, t2, 0); issueA(buf, t2, 64); issueA(buf, t2, 128); issueA(buf, t2, 192);\
      issueB(buf, t2, 0); issueB(buf, t2, 64); issueB(buf, t2, 128); issueB(buf, t2, 192); }
#define BAR()    __builtin_amdgcn_s_barrier()
#define LGKM0()  asm volatile("s_waitcnt lgkmcnt(0)" ::: "memory")
#define VMCNT0() asm volatile("s_waitcnt vmcnt(0)" ::: "memory")

    // prologue: stage tile 0 into buf0, drain, barrier
    STAGE8(0, 0);
    VMCNT0();
    BAR();

#define TILE_BODY(bp, bq, tn, PRE)                                                        \
    /* ---- P1: stage-all(t+1) ; RD(rh0,ks0)+RD_B(ks0) ; MFMA ---- */                     \
    if (PRE) STAGE8(bq, tn);                                                              \
    RD_A(bp, 0, 0, aA); RD_B(bp, 0, B0);                                                  \
    BAR(); LGKM0();                                                                       \
    MF16(0, aA, B0);                                                                      \
    BAR();                                                                                \
    /* ---- P2: RD(rh0,ks1)+RD_B(ks1) ; MFMA ---- */                                      \
    RD_A(bp, 0, 1, aB); RD_B(bp, 1, B1);                                                  \
    BAR(); LGKM0();                                                                       \
    MF16(0, aB, B1);                                                                      \
    BAR();                                                                                \
    /* ---- P3: RD(rh1,ks0) ; MFMA reuses B0 ---- */                                      \
    RD_A(bp, 1, 0, aA);                                                                   \
    BAR(); LGKM0();                                                                       \
    MF16(1, aA, B0);                                                                      \
    BAR();                                                                                \
    /* ---- P4: RD(rh1,ks1) ; MFMA reuses B1 ; drain t+1 stages ---- */                   \
    RD_A(bp, 1, 1, aB);                                                                   \
    BAR(); LGKM0();                                                                       \
    MF16(1, aB, B1);                                                                      \
    VMCNT0();                                                                             \
    BAR();

    for (int t = 0; t < nt; t += 2) {
        TILE_BODY(0, 1, t + 1, true);                 // even tile: stages t+1 (t+1 < nt)
        const bool pre2 = (t + 2) < nt;
        TILE_BODY(1, 0, t + 2, pre2);                 // odd tile: stages t+2 if any
    }
#undef TILE_BODY
#undef RD_A
#undef RD_B
#undef MF16
#undef STAGE8
#undef BAR
#undef LGKM0
#undef VMCNT0

    // epilogue: C/D layout row=quad*4+reg, col=l15
    #pragma unroll
    for (int i = 0; i < 8; ++i) {
        const int row = m0 + wr * 128 + i * 16 + quad * 4;
        #pragma unroll
        for (int j = 0; j < 4; ++j) {
            const int col = n0 + wc * 64 + j * 16 + l15;
            const float bv = bias ? bias[col] : 0.f;
            #pragma unroll
            for (int r = 0; r < 4; ++r) {
                float vv = acc[i][j][r] + bv;
                if (ACT == 1) vv = fast_gelu(vv);
                C[(size_t)(row + r) * ldc + col] = f2b(vv);
            }
        }
    }
}

extern "C" void kernel_launch(void* const* d_in, const int* in_sizes, int n_in,
                              void* d_out, int out_size, void* d_ws, size_t ws_size,
                              hipStream_t stream)
{
    (void)in_sizes; (void)n_in; (void)out_size; (void)ws_size;
    const float* x     = (const float*)d_in[0];
    const float* ln1g  = (const float*)d_in[1];
    const float* ln1b  = (const float*)d_in[2];
    const float* Wqkv  = (const float*)d_in[3];
    const float* bqkv  = (const float*)d_in[4];
    const float* Wproj = (const float*)d_in[5];
    const float* bproj = (const float*)d_in[6];
    const float* ln2g  = (const float*)d_in[7];
    const float* ln2b  = (const float*)d_in[8];
    const float* W1    = (const float*)d_in[9];
    const float* b1    = (const float*)d_in[10];
    const float* W2    = (const float*)d_in[11];
    const float* b2    = (const float*)d_in[12];
    float* out = (float*)d_out;

    // ---- workspace arena (bf16 elements) ----
    char* ws = (char*)d_ws;
    size_t off = 0;
    auto alloc = [&](size_t elems) { bf16* p = (bf16*)(ws + off); off += elems * sizeof(bf16); return p; };
    bf16* WqkvT  = alloc(3072UL * 1024);
    bf16* WprojT = alloc(1024UL * 1024);
    bf16* W1T    = alloc(4096UL * 1024);
    bf16* W2T    = alloc(1024UL * 4096);
    bf16* h      = alloc(8192UL * 1024);        // LN1 out; later reused as `a`
    bf16* kqv    = alloc(8192UL * 3072);        // per-row k|q|v
    bf16* vT     = alloc(4UL * 1024 * 2048);
    bf16* attn   = alloc(4UL * 2048 * 2048);    // unnormalized exp'd scores
    // aliases (lifetimes disjoint):
    bf16* a   = h;
    bf16* p   = kqv;
    bf16* h2  = kqv + 8192UL * 1024;
    bf16* m   = kqv + 2UL * 8192 * 1024;        // spans kqv-tail + vT + attn

    const long T3D = (long)Tq * 3072, TT = (long)Tq * Tq, DT = (long)Dq * Tq, TD = (long)Tq * Dq;

    // prep: LN1 + all 4 weight transposes in one dispatch
    prep_kernel<<<11264, 256, 0, stream>>>(x, ln1g, ln1b, h,
                                           Wqkv, WqkvT, Wproj, WprojT, W1, W1T, W2, W2T);

    // kqv = h @ Wqkv + bqkv    [8192, 3072]   (256^2 v5 engine, 384 blocks)
    gemm256<0><<<dim3(12, 32, 1), 512, 0, stream>>>(h, WqkvT, bqkv, kqv,
        1024, 1024L, 1024L, 3072L);

    // P-hat = exp(q @ k^T / sqrt(T)) causal, triangular grid (136 tiles/batch)
    // + fused V->V^T transpose in blocks 136..647
    gemm128<2,1,0,0><<<dim3(648, 1, 4), 256, 0, stream>>>(kqv + 1024, kqv, nullptr, attn, nullptr,
        1024, 3072L, 3072L, 2048L, T3D, T3D, TT, 0.022097086912079608f, kqv + 2048, vT);

    // a = (P-hat @ V) * rcp(rowsum)   (K truncated to m0+128; rowsum fused via ones-MFMA)
    gemm128<0,0,1,1><<<dim3(8, 16, 4), 256, 0, stream>>>(attn, vT, nullptr, a, nullptr,
        2048, 2048L, 2048L, 1024L, TT, DT, TD, 1.f, nullptr, nullptr);

    // p = a @ Wproj + bproj
    gemm128<0,0,0,0><<<dim3(8, 64, 1), 256, 0, stream>>>(a, WprojT, bproj, p, nullptr,
        1024, 1024L, 1024L, 1024L, 0L, 0L, 0L, 1.f, nullptr, nullptr);

    ln_kernel<<<8192, 256, 0, stream>>>(p, ln2g, ln2b, h2);

    // m = gelu(h2 @ W1 + b1)   [8192, 4096]   (256^2 v5 engine, 512 blocks)
    gemm256<1><<<dim3(16, 32, 1), 512, 0, stream>>>(h2, W1T, b1, m,
        1024, 1024L, 1024L, 4096L);

    // out = m @ W2 + b2        [8192, 1024]  (fp32 out; N=1024 -> only 128 blocks
    // at 256^2 so keep the 128^2 engine here)
    gemm128<0,0,0,0><<<dim3(8, 64, 1), 256, 0, stream>>>(m, W2T, b2, nullptr, out,
        4096, 4096L, 4096L, 1024L, 0L, 0L, 0L, 1.f, nullptr, nullptr);
}

// Round 6
// 466.436 us; speedup vs baseline: 1.0689x; 1.0689x over previous
//
#include <hip/hip_runtime.h>
#include <hip/hip_bf16.h>

typedef __hip_bfloat16 bf16;
typedef __bf16 bf16x8 __attribute__((ext_vector_type(8)));
typedef __bf16 bf16x4 __attribute__((ext_vector_type(4)));
typedef __bf16 bf16x2 __attribute__((ext_vector_type(2)));
typedef float f32x4 __attribute__((ext_vector_type(4)));

static constexpr int Bq = 4, Tq = 2048, Dq = 1024;

__device__ inline float b2f(bf16 h) { return __bfloat162float(h); }
__device__ inline bf16 f2b(float f) { return __float2bfloat16(f); }

// async global->LDS, 16 B per lane. LDS dst = wave-uniform base + lane*16.
__device__ __forceinline__ void gload_lds16(const bf16* g, bf16* lds_wave_base) {
    __builtin_amdgcn_global_load_lds((const __attribute__((address_space(1))) void*)g,
                                     (__attribute__((address_space(3))) void*)lds_wave_base,
                                     16, 0, 0);
}

// fast tanh-approx GELU: x * sigmoid(1.5957691x + 0.0713548x^3), via exp2+rcp
__device__ __forceinline__ float fast_gelu(float x) {
    float u = x * (0.7978845608028654f + 0.03567740814183427f * x * x);
    float e = __builtin_amdgcn_exp2f(-2.885390081777927f * u);
    return x * __builtin_amdgcn_rcpf(1.f + e);
}

__device__ inline void ld4f(const float* p, float* v) {
    float4 t = *reinterpret_cast<const float4*>(p);
    v[0] = t.x; v[1] = t.y; v[2] = t.z; v[3] = t.w;
}
__device__ inline void ld4f(const bf16* p, float* v) {
    bf16x4 t = *reinterpret_cast<const bf16x4*>(p);
    v[0] = (float)t[0]; v[1] = (float)t[1]; v[2] = (float)t[2]; v[3] = (float)t[3];
}

// ---------------- LayerNorm body (one block per row, D=1024), fp32 gamma/beta ----------------
template <typename Tin>
__device__ __forceinline__ void ln_body(const Tin* __restrict__ x, const float* __restrict__ g,
                                        const float* __restrict__ b, bf16* __restrict__ out,
                                        int row, float* sred)
{
    const int tid = threadIdx.x;
    const int s0 = tid * 4;
    const Tin* xr = x + (size_t)row * Dq;
    bf16* orow = out + (size_t)row * Dq;
    float v[4], gv[4], bv[4];
    ld4f(xr + s0, v);
    ld4f(g + s0, gv);
    ld4f(b + s0, bv);
    float sum = v[0] + v[1] + v[2] + v[3];
    float sq = v[0]*v[0] + v[1]*v[1] + v[2]*v[2] + v[3]*v[3];
    for (int o = 32; o > 0; o >>= 1) { sum += __shfl_xor(sum, o); sq += __shfl_xor(sq, o); }
    const int w = tid >> 6;
    if ((tid & 63) == 0) { sred[w] = sum; sred[4 + w] = sq; }
    __syncthreads();
    const float ts = sred[0] + sred[1] + sred[2] + sred[3];
    const float tq = sred[4] + sred[5] + sred[6] + sred[7];
    const float mean = ts / Dq;
    const float rs = rsqrtf(tq / Dq - mean * mean + 1e-5f);
    bf16x4 o4;
    #pragma unroll
    for (int i = 0; i < 4; ++i) o4[i] = (__bf16)((v[i] - mean) * rs * gv[i] + bv[i]);
    *reinterpret_cast<bf16x4*>(orow + s0) = o4;
}

__global__ void ln_kernel(const bf16* __restrict__ x, const float* __restrict__ g,
                          const float* __restrict__ b, bf16* __restrict__ out)
{
    __shared__ float sred[8];
    ln_body(x, g, b, out, blockIdx.x, sred);
}

// ---------------- prep: LN1 (8192 blocks) + 4 weight transposes (3072 tile-blocks) ----------------
__global__ void prep_kernel(const float* __restrict__ x, const float* __restrict__ g,
                            const float* __restrict__ b, bf16* __restrict__ h,
                            const float* __restrict__ Wqkv, bf16* __restrict__ WqkvT,
                            const float* __restrict__ Wproj, bf16* __restrict__ WprojT,
                            const float* __restrict__ W1, bf16* __restrict__ W1T,
                            const float* __restrict__ W2, bf16* __restrict__ W2T)
{
    __shared__ float smem[64 * 65];
    int id = blockIdx.x;
    if (id < 8192) { ln_body(x, g, b, h, id, smem); return; }
    id -= 8192;
    const float* src; bf16* dst; long ldin, ldout; int gx;
    if (id < 768)       { src = Wqkv;  dst = WqkvT;  ldin = 3072; ldout = 1024; gx = 48; }
    else if (id < 1024) { id -= 768;  src = Wproj; dst = WprojT; ldin = 1024; ldout = 1024; gx = 16; }
    else if (id < 2048) { id -= 1024; src = W1;    dst = W1T;    ldin = 4096; ldout = 1024; gx = 64; }
    else                { id -= 2048; src = W2;    dst = W2T;    ldin = 1024; ldout = 4096; gx = 16; }
    const int c0 = (id % gx) * 64, r0 = (id / gx) * 64;
    const int tid = threadIdx.x;
    const int tx = tid & 63, ty = tid >> 6;
    float (*tile)[65] = reinterpret_cast<float(*)[65]>(smem);
    #pragma unroll
    for (int i = 0; i < 16; ++i) {
        int r = ty + i * 4;
        tile[r][tx] = src[(size_t)(r0 + r) * ldin + c0 + tx];
    }
    __syncthreads();
    const int px = tid & 31, cy = tid >> 5;
    #pragma unroll
    for (int i = 0; i < 8; ++i) {
        int cc = cy + i * 8;
        bf16x2 p;
        p[0] = (__bf16)tile[px * 2][cc];
        p[1] = (__bf16)tile[px * 2 + 1][cc];
        *reinterpret_cast<bf16x2*>(&dst[(size_t)(c0 + cc) * ldout + r0 + px * 2]) = p;
    }
}

// ---------------- 128x128 LDS-staged MFMA GEMM, BK=64 (R8 inner loop) ----------------
// C = act(scale * A @ Bt^T + bias). A:[M,K] (lda), Bt:[N,K] (ldb), bf16.
// ACT: 0 none, 1 gelu, 2 exp2 w/ causal mask. TRI: lower-triangle grid decode;
//      blocks 136..647 of a TRI dispatch do the V->V^T transpose instead.
// CK: truncate K at m0+128 (attn@V). FR: fused row-sum via all-ones-B MFMA.
template <int ACT, int TRI, int CK, int FR>
__global__ void gemm128(const bf16* __restrict__ A, const bf16* __restrict__ Bt,
                        const float* __restrict__ bias,
                        bf16* __restrict__ Cb, float* __restrict__ Cf,
                        int K, long lda, long ldb, long ldc,
                        long sA, long sB, long sC, float scale,
                        const bf16* __restrict__ vsrc, bf16* __restrict__ vdst)
{
    __shared__ bf16 As[128 * 64];
    __shared__ bf16 Bs[128 * 64];

    int bx, by;
    if (TRI) {
        const int lin = blockIdx.x;
        if (lin >= 136) {
            // ---- fused V -> V^T 64x64 tile transpose (V cols of kqv); 512 tiles/batch ----
            const int idx = lin - 136;
            const int c0 = (idx & 15) * 64, r0 = (idx >> 4) * 64;
            const bf16* ip = vsrc + (size_t)blockIdx.z * ((size_t)Tq * 3072);
            bf16* op = vdst + (size_t)blockIdx.z * ((size_t)Dq * Tq);
            bf16 (*tile)[66] = reinterpret_cast<bf16(*)[66]>(As);
            const int tid = threadIdx.x;
            const int tx = tid & 31, ty = tid >> 5;
            #pragma unroll
            for (int i = 0; i < 8; ++i) {
                int r = ty + i * 8;
                *reinterpret_cast<bf16x2*>(&tile[r][tx * 2]) =
                    *reinterpret_cast<const bf16x2*>(&ip[(size_t)(r0 + r) * 3072 + c0 + tx * 2]);
            }
            __syncthreads();
            #pragma unroll
            for (int i = 0; i < 8; ++i) {
                int cc = ty + i * 8;
                bf16x2 p;
                p[0] = tile[tx * 2][cc];
                p[1] = tile[tx * 2 + 1][cc];
                *reinterpret_cast<bf16x2*>(&op[(size_t)(c0 + cc) * 2048 + r0 + tx * 2]) = p;
            }
            return;
        }
        int t = (int)((sqrtf(8.f * lin + 1.f) - 1.f) * 0.5f);
        while ((t + 1) * (t + 2) / 2 <= lin) ++t;
        while (t * (t + 1) / 2 > lin) --t;
        by = t; bx = lin - t * (t + 1) / 2;
    } else {
        // XCD-banded remap (bijective; gy % 8 == 0 for all our grids)
        const int gx = gridDim.x, gy = gridDim.y;
        const int lin = blockIdx.x + gx * blockIdx.y;
        const int band = lin & 7;
        const int idx = lin >> 3;
        bx = idx % gx;
        by = band * (gy >> 3) + idx / gx;
    }

    const int m0 = by * 128, n0 = bx * 128;
    const int Kend = CK ? min(K, m0 + 128) : K;

    const bf16* Ab = A + (size_t)blockIdx.z * sA;
    const bf16* Bb = Bt + (size_t)blockIdx.z * sB;
    const int tid = threadIdx.x;
    const int wid = tid >> 6, lane = tid & 63;
    const int wr = wid >> 1, wc = wid & 1;
    const int l15 = lane & 15, quad = lane >> 4;

    const int rloc = lane >> 3, slot = lane & 7;
    const bf16* agp = Ab + (size_t)(m0 + wid * 32 + rloc) * lda + (slot ^ rloc) * 8;
    const bf16* bgp = Bb + (size_t)(n0 + wid * 32 + rloc) * ldb + (slot ^ rloc) * 8;
    bf16* awb = As + wid * 32 * 64;
    bf16* bwb = Bs + wid * 32 * 64;

    const int afo = (wr * 64 + l15) * 64 + ((quad ^ (l15 & 7)) * 8);
    const int bfo = (wc * 64 + l15) * 64 + ((quad ^ (l15 & 7)) * 8);

    f32x4 acc[4][4];
    #pragma unroll
    for (int i = 0; i < 4; ++i)
        #pragma unroll
        for (int j = 0; j < 4; ++j) acc[i][j] = (f32x4){0.f, 0.f, 0.f, 0.f};

    f32x4 acc_l[4];
    bf16x8 ones;
    if (FR) {
        #pragma unroll
        for (int i = 0; i < 4; ++i) acc_l[i] = (f32x4){0.f, 0.f, 0.f, 0.f};
        #pragma unroll
        for (int i = 0; i < 8; ++i) ones[i] = (__bf16)1.0f;
    }

    for (int k0 = 0; k0 < Kend; k0 += 64) {
        #pragma unroll
        for (int i = 0; i < 4; ++i) {
            gload_lds16(agp + k0 + (size_t)(i * 8) * lda, awb + i * 8 * 64);
            gload_lds16(bgp + k0 + (size_t)(i * 8) * ldb, bwb + i * 8 * 64);
        }
        __syncthreads();

        bf16x8 af0[4], bf0[4], af1[4], bf1[4];
        #pragma unroll
        for (int i = 0; i < 4; ++i) {
            af0[i] = *reinterpret_cast<const bf16x8*>(As + (afo ^ 0)  + i * 1024);
            af1[i] = *reinterpret_cast<const bf16x8*>(As + (afo ^ 32) + i * 1024);
        }
        #pragma unroll
        for (int j = 0; j < 4; ++j) {
            bf0[j] = *reinterpret_cast<const bf16x8*>(Bs + (bfo ^ 0)  + j * 1024);
            bf1[j] = *reinterpret_cast<const bf16x8*>(Bs + (bfo ^ 32) + j * 1024);
        }
        #pragma unroll
        for (int i = 0; i < 4; ++i)
            #pragma unroll
            for (int j = 0; j < 4; ++j)
                acc[i][j] = __builtin_amdgcn_mfma_f32_16x16x32_bf16(af0[i], bf0[j], acc[i][j], 0, 0, 0);
        if (FR) {
            #pragma unroll
            for (int i = 0; i < 4; ++i)
                acc_l[i] = __builtin_amdgcn_mfma_f32_16x16x32_bf16(af0[i], ones, acc_l[i], 0, 0, 0);
        }
        #pragma unroll
        for (int i = 0; i < 4; ++i)
            #pragma unroll
            for (int j = 0; j < 4; ++j)
                acc[i][j] = __builtin_amdgcn_mfma_f32_16x16x32_bf16(af1[i], bf1[j], acc[i][j], 0, 0, 0);
        if (FR) {
            #pragma unroll
            for (int i = 0; i < 4; ++i)
                acc_l[i] = __builtin_amdgcn_mfma_f32_16x16x32_bf16(af1[i], ones, acc_l[i], 0, 0, 0);
        }

        __syncthreads();
    }

    #pragma unroll
    for (int i = 0; i < 4; ++i) {
        const int row = m0 + wr * 64 + i * 16 + quad * 4;
        #pragma unroll
        for (int j = 0; j < 4; ++j) {
            const int col = n0 + wc * 64 + j * 16 + l15;
            const float bv = bias ? bias[col] : 0.f;
            #pragma unroll
            for (int r = 0; r < 4; ++r) {
                float vv = scale * acc[i][j][r] + bv;
                if (ACT == 1) vv = fast_gelu(vv);
                else if (ACT == 2)
                    vv = (col <= row + r) ? __builtin_amdgcn_exp2f(1.4426950408889634f * vv) : 0.f;
                if (FR) vv *= __builtin_amdgcn_rcpf(acc_l[i][r]);
                const size_t idx2 = (size_t)(row + r) * ldc + col + (size_t)blockIdx.z * sC;
                if (Cf) Cf[idx2] = vv;
                else    Cb[idx2] = f2b(vv);
            }
        }
    }
}

// ---------------- 256x256 single-barrier-per-tile MFMA GEMM, BK=64 (v4, round-4 verified) ----------------
// 512 threads = 8 waves (2M x 4N), per-wave C = 128x64. Ring-2 LDS (128 KiB).
//  - ONE s_barrier per K-tile (at tile end). Cross-wave hazards: stage(bq) vs bq's
//    readers separated by the PREVIOUS tile-end barrier; reads(bp) vs bp's stagers
//    separated by {stager's own vmcnt(0) -> barrier}.
//  - ds_reads issued BETWEEN MFMA clusters, waits left to compiler-counted lgkmcnt
//    -> LDS traffic (24 reads/wave/tile, B held in regs) overlaps the MFMA stream.
//  - stage burst (8 issues) mid-tile; single vmcnt(0) at tile end (~2 phases cover).
template <int ACT>
__global__ __launch_bounds__(512) void gemm256(
        const bf16* __restrict__ A, const bf16* __restrict__ Bt,
        const float* __restrict__ bias, bf16* __restrict__ C,
        int K, long lda, long ldb, long ldc)
{
    __shared__ bf16 As[2][256 * 64];
    __shared__ bf16 Bs[2][256 * 64];

    // XCD-banded remap (gy % 8 == 0 for all our grids)
    const int gx = gridDim.x, gy = gridDim.y;
    const int lin = blockIdx.x + gx * blockIdx.y;
    const int band = lin & 7;
    const int idx = lin >> 3;
    const int bx = idx % gx;
    const int by = band * (gy >> 3) + idx / gx;
    const int m0 = by * 256, n0 = bx * 256;

    const int tid = threadIdx.x;
    const int wid = tid >> 6, lane = tid & 63;
    const int wr = wid >> 2, wc = wid & 3;
    const int l15 = lane & 15, quad = lane >> 4;
    const int rloc = lane >> 3, slot = lane & 7;

    const bf16* agp = A + (size_t)(m0 + wid * 8 + rloc) * lda + (slot ^ rloc) * 8;
    const bf16* bgp = Bt + (size_t)(n0 + wid * 8 + rloc) * ldb + (slot ^ rloc) * 8;

    auto issueA = [&](int buf, int t2, int R) {
        gload_lds16(agp + (size_t)R * lda + t2 * 64, &As[buf][(R + wid * 8) * 64]);
    };
    auto issueB = [&](int buf, int t2, int R) {
        gload_lds16(bgp + (size_t)R * ldb + t2 * 64, &Bs[buf][(R + wid * 8) * 64]);
    };

    const int xg = (quad ^ (l15 & 7)) * 8;
    const int afo = (wr * 128 + l15) * 64 + xg;
    const int bfo = (wc * 64 + l15) * 64 + xg;

    f32x4 acc[8][4];
    #pragma unroll
    for (int i = 0; i < 8; ++i)
        #pragma unroll
        for (int j = 0; j < 4; ++j) acc[i][j] = (f32x4){0.f, 0.f, 0.f, 0.f};

    bf16x8 aA[4], aB[4], B0[4], B1[4];

    const int nt = K >> 6;   // even for all our shapes (K=1024)

#define RD_A(buf, rh, ks, dst)                                                            \
    { _Pragma("unroll")                                                                   \
      for (int i_ = 0; i_ < 4; ++i_)                                                      \
          dst[i_] = *reinterpret_cast<const bf16x8*>(                                     \
              &As[buf][(afo + (rh) * 4096 + i_ * 1024) ^ ((ks) * 32)]); }
#define RD_B(buf, ks, dst)                                                                \
    { _Pragma("unroll")                                                                   \
      for (int j_ = 0; j_ < 4; ++j_)                                                      \
          dst[j_] = *reinterpret_cast<const bf16x8*>(                                     \
              &Bs[buf][(bfo + j_ * 1024) ^ ((ks) * 32)]); }
#define MF8(rh, Aset, Bset, I0)                                                           \
    { __builtin_amdgcn_s_setprio(1);                                                      \
      _Pragma("unroll")                                                                   \
      for (int i_ = (I0); i_ < (I0) + 2; ++i_)                                            \
          _Pragma("unroll")                                                               \
          for (int j_ = 0; j_ < 4; ++j_)                                                  \
              acc[(rh) * 4 + i_][j_] = __builtin_amdgcn_mfma_f32_16x16x32_bf16(           \
                  Aset[i_], Bset[j_], acc[(rh) * 4 + i_][j_], 0, 0, 0);                   \
      __builtin_amdgcn_s_setprio(0); }
#define STAGE8(buf, t2)                                                                   \
    { issueA(buf, t2, 0); issueA(buf, t2, 64); issueA(buf, t2, 128); issueA(buf, t2, 192);\
      issueB(buf, t2, 0); issueB(buf, t2, 64); issueB(buf, t2, 128); issueB(buf, t2, 192); }
#define BAR()    __builtin_amdgcn_s_barrier()
#define CFENCE() asm volatile("" ::: "memory")
#define VMCNT0() asm volatile("s_waitcnt vmcnt(0)" ::: "memory")

    STAGE8(0, 0);
    VMCNT0();
    CFENCE(); BAR(); CFENCE();

#define TILE_BODY(bp, bq, tn, PRE)                                                        \
    RD_A(bp, 0, 0, aA); RD_B(bp, 0, B0); RD_B(bp, 1, B1);                                 \
    MF8(0, aA, B0, 0);                                                                    \
    RD_A(bp, 0, 1, aB);                                                                   \
    MF8(0, aA, B0, 2);                                                                    \
    MF8(0, aB, B1, 0);                                                                    \
    RD_A(bp, 1, 0, aA);                                                                   \
    if (PRE) STAGE8(bq, tn);                                                              \
    MF8(0, aB, B1, 2);                                                                    \
    MF8(1, aA, B0, 0);                                                                    \
    RD_A(bp, 1, 1, aB);                                                                   \
    MF8(1, aA, B0, 2);                                                                    \
    MF8(1, aB, B1, 0);                                                                    \
    MF8(1, aB, B1, 2);                                                                    \
    VMCNT0();                                                                             \
    CFENCE(); BAR(); CFENCE();

    for (int t = 0; t < nt; t += 2) {
        TILE_BODY(0, 1, t + 1, true);
        const bool pre2 = (t + 2) < nt;
        TILE_BODY(1, 0, t + 2, pre2);
    }
#undef TILE_BODY
#undef RD_A
#undef RD_B
#undef MF8
#undef STAGE8
#undef BAR
#undef CFENCE
#undef VMCNT0

    #pragma unroll
    for (int i = 0; i < 8; ++i) {
        const int row = m0 + wr * 128 + i * 16 + quad * 4;
        #pragma unroll
        for (int j = 0; j < 4; ++j) {
            const int col = n0 + wc * 64 + j * 16 + l15;
            const float bv = bias ? bias[col] : 0.f;
            #pragma unroll
            for (int r = 0; r < 4; ++r) {
                float vv = acc[i][j][r] + bv;
                if (ACT == 1) vv = fast_gelu(vv);
                C[(size_t)(row + r) * ldc + col] = f2b(vv);
            }
        }
    }
}

// ---------------- 128x256 single-barrier-per-tile MFMA GEMM, BK=64 (v4-style) ----------------
// For N=1024 outputs (MLP2, proj): grid (N/256) x (M/128) = 4 x 64 = 256 blocks = 1/CU.
// 512 threads = 8 waves (2M x 4N), per-wave C = 64x64: 16 ds_reads vs 32 MFMA per
// wave per K-tile (per-CU: LDS 1536 cyc vs MFMA 1241 cyc -> near-balanced).
// Same v4 schedule: one barrier/K-tile, reads between MFMA clusters (compiler
// lgkm waits), STAGE6 mid-tile, single vmcnt(0) at tile end. LDS 96 KiB ring-2.
template <int ACT>
__global__ __launch_bounds__(512) void gemm128x256(
        const bf16* __restrict__ A, const bf16* __restrict__ Bt,
        const float* __restrict__ bias,
        bf16* __restrict__ Cb, float* __restrict__ Cf,
        int K, long lda, long ldb, long ldc)
{
    __shared__ bf16 As[2][128 * 64];
    __shared__ bf16 Bs[2][256 * 64];

    // XCD-banded remap (gy = 64, % 8 == 0)
    const int gx = gridDim.x, gy = gridDim.y;
    const int lin = blockIdx.x + gx * blockIdx.y;
    const int band = lin & 7;
    const int idx = lin >> 3;
    const int bx = idx % gx;
    const int by = band * (gy >> 3) + idx / gx;
    const int m0 = by * 128, n0 = bx * 256;

    const int tid = threadIdx.x;
    const int wid = tid >> 6, lane = tid & 63;
    const int wr = wid >> 2, wc = wid & 3;            // wr: 2 row-halves, wc: 4 col-blocks
    const int l15 = lane & 15, quad = lane >> 4;
    const int rloc = lane >> 3, slot = lane & 7;

    const bf16* agp = A + (size_t)(m0 + wid * 8 + rloc) * lda + (slot ^ rloc) * 8;
    const bf16* bgp = Bt + (size_t)(n0 + wid * 8 + rloc) * ldb + (slot ^ rloc) * 8;

    auto issueA = [&](int buf, int t2, int R) {
        gload_lds16(agp + (size_t)R * lda + t2 * 64, &As[buf][(R + wid * 8) * 64]);
    };
    auto issueB = [&](int buf, int t2, int R) {
        gload_lds16(bgp + (size_t)R * ldb + t2 * 64, &Bs[buf][(R + wid * 8) * 64]);
    };

    const int xg = (quad ^ (l15 & 7)) * 8;
    const int afo = (wr * 64 + l15) * 64 + xg;        // wave rows: wr*64 .. +63
    const int bfo = (wc * 64 + l15) * 64 + xg;        // wave cols: wc*64 .. +63

    f32x4 acc[4][4];
    #pragma unroll
    for (int i = 0; i < 4; ++i)
        #pragma unroll
        for (int j = 0; j < 4; ++j) acc[i][j] = (f32x4){0.f, 0.f, 0.f, 0.f};

    bf16x8 aA[4], aB[4], B0[4], B1[4];

    const int nt = K >> 6;   // 64 (MLP2) / 16 (proj) — even

#define RD_A(buf, ks, dst)                                                                \
    { _Pragma("unroll")                                                                   \
      for (int i_ = 0; i_ < 4; ++i_)                                                      \
          dst[i_] = *reinterpret_cast<const bf16x8*>(                                     \
              &As[buf][(afo + i_ * 1024) ^ ((ks) * 32)]); }
#define RD_B(buf, ks, dst)                                                                \
    { _Pragma("unroll")                                                                   \
      for (int j_ = 0; j_ < 4; ++j_)                                                      \
          dst[j_] = *reinterpret_cast<const bf16x8*>(                                     \
              &Bs[buf][(bfo + j_ * 1024) ^ ((ks) * 32)]); }
#define MF8(Aset, Bset, I0)                                                               \
    { __builtin_amdgcn_s_setprio(1);                                                      \
      _Pragma("unroll")                                                                   \
      for (int i_ = (I0); i_ < (I0) + 2; ++i_)                                            \
          _Pragma("unroll")                                                               \
          for (int j_ = 0; j_ < 4; ++j_)                                                  \
              acc[i_][j_] = __builtin_amdgcn_mfma_f32_16x16x32_bf16(                      \
                  Aset[i_], Bset[j_], acc[i_][j_], 0, 0, 0);                              \
      __builtin_amdgcn_s_setprio(0); }
#define STAGE6(buf, t2)                                                                   \
    { issueA(buf, t2, 0); issueA(buf, t2, 64);                                            \
      issueB(buf, t2, 0); issueB(buf, t2, 64); issueB(buf, t2, 128); issueB(buf, t2, 192); }
#define BAR()    __builtin_amdgcn_s_barrier()
#define CFENCE() asm volatile("" ::: "memory")
#define VMCNT0() asm volatile("s_waitcnt vmcnt(0)" ::: "memory")

    STAGE6(0, 0);
    VMCNT0();
    CFENCE(); BAR(); CFENCE();

#define TILE_BODY(bp, bq, tn, PRE)                                                        \
    RD_A(bp, 0, aA); RD_B(bp, 0, B0);                                                     \
    MF8(aA, B0, 0);                                                                       \
    RD_A(bp, 1, aB); RD_B(bp, 1, B1);                                                     \
    MF8(aA, B0, 2);                                                                       \
    if (PRE) STAGE6(bq, tn);                                                              \
    MF8(aB, B1, 0);                                                                       \
    MF8(aB, B1, 2);                                                                       \
    VMCNT0();                                                                             \
    CFENCE(); BAR(); CFENCE();

    for (int t = 0; t < nt; t += 2) {
        TILE_BODY(0, 1, t + 1, true);
        const bool pre2 = (t + 2) < nt;
        TILE_BODY(1, 0, t + 2, pre2);
    }
#undef TILE_BODY
#undef RD_A
#undef RD_B
#undef MF8
#undef STAGE6
#undef BAR
#undef CFENCE
#undef VMCNT0

    // epilogue: C/D layout row=quad*4+reg, col=l15
    #pragma unroll
    for (int i = 0; i < 4; ++i) {
        const int row = m0 + wr * 64 + i * 16 + quad * 4;
        #pragma unroll
        for (int j = 0; j < 4; ++j) {
            const int col = n0 + wc * 64 + j * 16 + l15;
            const float bv = bias ? bias[col] : 0.f;
            #pragma unroll
            for (int r = 0; r < 4; ++r) {
                float vv = acc[i][j][r] + bv;
                if (ACT == 1) vv = fast_gelu(vv);
                const size_t idx2 = (size_t)(row + r) * ldc + col;
                if (Cf) Cf[idx2] = vv;
                else    Cb[idx2] = f2b(vv);
            }
        }
    }
}

extern "C" void kernel_launch(void* const* d_in, const int* in_sizes, int n_in,
                              void* d_out, int out_size, void* d_ws, size_t ws_size,
                              hipStream_t stream)
{
    (void)in_sizes; (void)n_in; (void)out_size; (void)ws_size;
    const float* x     = (const float*)d_in[0];
    const float* ln1g  = (const float*)d_in[1];
    const float* ln1b  = (const float*)d_in[2];
    const float* Wqkv  = (const float*)d_in[3];
    const float* bqkv  = (const float*)d_in[4];
    const float* Wproj = (const float*)d_in[5];
    const float* bproj = (const float*)d_in[6];
    const float* ln2g  = (const float*)d_in[7];
    const float* ln2b  = (const float*)d_in[8];
    const float* W1    = (const float*)d_in[9];
    const float* b1    = (const float*)d_in[10];
    const float* W2    = (const float*)d_in[11];
    const float* b2    = (const float*)d_in[12];
    float* out = (float*)d_out;

    // ---- workspace arena (bf16 elements) ----
    char* ws = (char*)d_ws;
    size_t off = 0;
    auto alloc = [&](size_t elems) { bf16* p = (bf16*)(ws + off); off += elems * sizeof(bf16); return p; };
    bf16* WqkvT  = alloc(3072UL * 1024);
    bf16* WprojT = alloc(1024UL * 1024);
    bf16* W1T    = alloc(4096UL * 1024);
    bf16* W2T    = alloc(1024UL * 4096);
    bf16* h      = alloc(8192UL * 1024);        // LN1 out; later reused as `a`
    bf16* kqv    = alloc(8192UL * 3072);        // per-row k|q|v
    bf16* vT     = alloc(4UL * 1024 * 2048);
    bf16* attn   = alloc(4UL * 2048 * 2048);    // unnormalized exp'd scores
    // aliases (lifetimes disjoint):
    bf16* a   = h;
    bf16* p   = kqv;
    bf16* h2  = kqv + 8192UL * 1024;
    bf16* m   = kqv + 2UL * 8192 * 1024;        // spans kqv-tail + vT + attn

    const long T3D = (long)Tq * 3072, TT = (long)Tq * Tq, DT = (long)Dq * Tq, TD = (long)Tq * Dq;

    // prep: LN1 + all 4 weight transposes in one dispatch
    prep_kernel<<<11264, 256, 0, stream>>>(x, ln1g, ln1b, h,
                                           Wqkv, WqkvT, Wproj, WprojT, W1, W1T, W2, W2T);

    // kqv = h @ Wqkv + bqkv    [8192, 3072]   (256^2 v4 engine, 384 blocks)
    gemm256<0><<<dim3(12, 32, 1), 512, 0, stream>>>(h, WqkvT, bqkv, kqv,
        1024, 1024L, 1024L, 3072L);

    // P-hat = exp(q @ k^T / sqrt(T)) causal, triangular grid (136 tiles/batch)
    // + fused V->V^T transpose in blocks 136..647
    gemm128<2,1,0,0><<<dim3(648, 1, 4), 256, 0, stream>>>(kqv + 1024, kqv, nullptr, attn, nullptr,
        1024, 3072L, 3072L, 2048L, T3D, T3D, TT, 0.022097086912079608f, kqv + 2048, vT);

    // a = (P-hat @ V) * rcp(rowsum)   (K truncated to m0+128; rowsum fused via ones-MFMA)
    gemm128<0,0,1,1><<<dim3(8, 16, 4), 256, 0, stream>>>(attn, vT, nullptr, a, nullptr,
        2048, 2048L, 2048L, 1024L, TT, DT, TD, 1.f, nullptr, nullptr);

    // p = a @ Wproj + bproj    [8192, 1024]   (128x256 engine, 256 blocks = 1/CU)
    gemm128x256<0><<<dim3(4, 64, 1), 512, 0, stream>>>(a, WprojT, bproj, p, nullptr,
        1024, 1024L, 1024L, 1024L);

    ln_kernel<<<8192, 256, 0, stream>>>(p, ln2g, ln2b, h2);

    // m = gelu(h2 @ W1 + b1)   [8192, 4096]   (256^2 v4 engine, 512 blocks)
    gemm256<1><<<dim3(16, 32, 1), 512, 0, stream>>>(h2, W1T, b1, m,
        1024, 1024L, 1024L, 4096L);

    // out = m @ W2 + b2        [8192, 1024]  (fp32 out; 128x256 engine, 256 blocks = 1/CU)
    gemm128x256<0><<<dim3(4, 64, 1), 512, 0, stream>>>(m, W2T, b2, nullptr, out,
        4096, 4096L, 4096L, 1024L);
}